// Round 7
// baseline (456.595 us; speedup 1.0000x reference)
//
#include <hip/hip_runtime.h>

#define BATCH  512
#define SEQ    1024
#define NT     64
#define CHUNK  64
#define NCHUNK (SEQ / CHUNK)

typedef float float4v __attribute__((ext_vector_type(4)));

#define GLDS16(gsrc, ldst) \
    __builtin_amdgcn_global_load_lds( \
        (const __attribute__((address_space(1))) unsigned int*)(gsrc), \
        (__attribute__((address_space(3))) unsigned int*)(ldst), 16, 0, 0)
#define GLDS4(gsrc, ldst) \
    __builtin_amdgcn_global_load_lds( \
        (const __attribute__((address_space(1))) unsigned int*)(gsrc), \
        (__attribute__((address_space(3))) unsigned int*)(ldst), 4, 0, 0)

// Exp-domain CRF forward (round-7). dp_t = q_t + C*t, W = e^q:
//   W' = exp(e_t) * (E'^T W),  E' = exp(trans - C)  (constant, 64 f32/lane).
// No exp/log/bpermute on the recurrence chain — the only per-step transcendental
// (exp(e_t)) depends only on inputs and is scheduled off-chain. Chain/step:
// ds_write_b32(W_j) -> 16x uniform-addr ds_read_b128 (broadcast) -> 64 f32 FMA
// (8 chains) -> mul/select. Per-chunk power-of-2 renorm (exact, tracked in kacc)
// keeps W in f32 range regardless of drift-estimate error. Mask path exact:
// m=0 -> W *= e^{-C}. Single wave per block: in-order DS pipe, no barriers.
__global__ __launch_bounds__(64, 1) void crf_kernel(
        const float* __restrict__ emis,
        const int*   __restrict__ tags,
        const float* __restrict__ mask,
        const float* __restrict__ trans,
        float*       __restrict__ out)
{
    const int b = blockIdx.x;
    const int j = threadIdx.x;

    __shared__ float lds_e[2][CHUNK * NT];        // 2 x 16 KB emission chunks
    __shared__ float lds_m[2][CHUNK];             // 2 x 256 B mask chunks
    __shared__ __align__(16) float Wl[NT];        // 256 B W-broadcast buffer

    const float CSH  = 4.658f;                    // ~ mean dp increment/step
    const float KINV = 0.0094866f;                // e^{-CSH} (masked path only)

    // ---- E' column per lane: Ec[i] = exp(trans[i][j] - CSH), straight-line ----
    float Ec[NT];
#define EC1(I) { float v = __expf(trans[(I)*NT + j] - CSH); \
                 asm volatile("" : "+v"(v)); Ec[I] = v; }
#define EC4(I)  EC1(I) EC1((I)+1) EC1((I)+2) EC1((I)+3)
#define EC16(I) EC4(I) EC4((I)+4) EC4((I)+8) EC4((I)+12)
    EC16(0) EC16(16) EC16(32) EC16(48)

    const float* eb = emis + (size_t)b * SEQ * NT;
    const float* mb = mask + (size_t)b * SEQ;

    // ---- stage chunk 0 into buffer 0 (17 DMA ops) ----
    {
        #pragma unroll
        for (int k = 0; k < 16; ++k)
            GLDS16(eb + k * 256 + j * 4, &lds_e[0][k * 256]);
        GLDS4(mb + j, &lds_m[0][0]);
    }

    float Wj = 1.0f;     // W_0 = exp(dp_0) = 1
    int kacc = 0;        // accumulated power-of-2 renorm exponent

    for (int c = 0; c < NCHUNK; ++c) {
        const int buf = c & 1;
        if (c + 1 < NCHUNK) {
            const float* src = eb + (c + 1) * CHUNK * NT;
            #pragma unroll
            for (int k = 0; k < 16; ++k)
                GLDS16(src + k * 256 + j * 4, &lds_e[buf ^ 1][k * 256]);
            GLDS4(mb + (c + 1) * CHUNK + j, &lds_m[buf ^ 1][0]);
            asm volatile("s_waitcnt vmcnt(17)" ::: "memory");  // chunk c landed
        } else {
            asm volatile("s_waitcnt vmcnt(0)" ::: "memory");
        }

        const float* ep = &lds_e[buf][0];
        const float* mp = &lds_m[buf][0];
        const float4v* wp4 = (const float4v*)Wl;

        #pragma unroll 2
        for (int tt = 0; tt < CHUNK; ++tt) {
            float e_t = ep[tt * NT + j];   // input-only, off the W chain
            float mk  = mp[tt];
            Wl[j] = Wj;                    // ds_write_b32; in-order same-wave
            float ee = __expf(e_t);        // off-chain transcendental

            float s0 = 0.f, s1 = 0.f, s2 = 0.f, s3 = 0.f;
            float s4 = 0.f, s5 = 0.f, s6 = 0.f, s7 = 0.f;
#define MVQ2(K) { float4v qa = wp4[2*(K)]; float4v qb = wp4[2*(K)+1]; \
            s0 = fmaf(qa.x, Ec[8*(K)+0], s0); \
            s1 = fmaf(qa.y, Ec[8*(K)+1], s1); \
            s2 = fmaf(qa.z, Ec[8*(K)+2], s2); \
            s3 = fmaf(qa.w, Ec[8*(K)+3], s3); \
            s4 = fmaf(qb.x, Ec[8*(K)+4], s4); \
            s5 = fmaf(qb.y, Ec[8*(K)+5], s5); \
            s6 = fmaf(qb.z, Ec[8*(K)+6], s6); \
            s7 = fmaf(qb.w, Ec[8*(K)+7], s7); }
            MVQ2(0) MVQ2(1) MVQ2(2) MVQ2(3)
            MVQ2(4) MVQ2(5) MVQ2(6) MVQ2(7)
            float S = ((s0 + s1) + (s2 + s3)) + ((s4 + s5) + (s6 + s7));

            float Wn = ee * S;
            Wj = (mk != 0.0f) ? Wn : Wj * KINV;   // exact masked semantics
        }

        // ---- per-chunk exact renorm: W *= 2^-k, k from lane-0 magnitude ----
        float r = Wl[0];                   // uniform-addr broadcast read
        int k = ilogbf(r);
        Wj = ldexpf(Wj, -k);
        kacc += k;
    }

    // ---- z = log(sum_j W_j) + C*SEQ + kacc*ln2 ----
    float s = Wj;
    #pragma unroll
    for (int off = 32; off >= 1; off >>= 1)
        s += __shfl_xor(s, off, 64);
    float z = __logf(s) + CSH * (float)SEQ + (float)kacc * 0.69314718f;

    // ---- gold score ----
    const int* tb = tags + b * SEQ;
    float acc = 0.0f;
    for (int sId = 1 + j; sId < SEQ; sId += 64) {
        int tc = tb[sId];
        int tp = tb[sId - 1];
        acc += (eb[sId * NT + tc] + trans[tp * NT + tc]) * mb[sId];
    }
    #pragma unroll
    for (int off = 32; off >= 1; off >>= 1)
        acc += __shfl_xor(acc, off, 64);

    if (j == 0)
        atomicAdd(out, (acc - z) * (1.0f / BATCH));
}

__global__ void zero_kernel(float* out) { if (threadIdx.x == 0) out[0] = 0.0f; }

extern "C" void kernel_launch(void* const* d_in, const int* in_sizes, int n_in,
                              void* d_out, int out_size, void* d_ws, size_t ws_size,
                              hipStream_t stream) {
    const float* emis  = (const float*)d_in[0];
    const int*   tags  = (const int*)d_in[1];
    const float* mask  = (const float*)d_in[2];
    const float* trans = (const float*)d_in[3];
    float* out = (float*)d_out;

    zero_kernel<<<1, 64, 0, stream>>>(out);
    crf_kernel<<<BATCH, 64, 0, stream>>>(emis, tags, mask, trans, out);
}